// Round 13
// baseline (222.655 us; speedup 1.0000x reference)
//
#include <hip/hip_runtime.h>

#define DD 128
#define NN 512
#define NODES 1024

typedef short bf16x8 __attribute__((ext_vector_type(8)));
typedef float f32x4 __attribute__((ext_vector_type(4)));
typedef float f32x2 __attribute__((ext_vector_type(2)));

__device__ __forceinline__ float sigmoidf_(float x) {
  return __builtin_amdgcn_rcpf(1.f + __expf(-x));
}
__device__ __forceinline__ float siluf_(float x) { return x * sigmoidf_(x); }

__device__ __forceinline__ unsigned short f2bf_(float v) {
  unsigned int u = __float_as_uint(v);
  u += 0x7fffu + ((u >> 16) & 1u);   // RNE
  return (unsigned short)(u >> 16);
}
__device__ __forceinline__ unsigned cvtpk_(float lo, float hi) {
  unsigned r;
  asm("v_cvt_pk_bf16_f32 %0, %1, %2" : "=v"(r) : "v"(lo), "v"(hi));
  return r;
}
__device__ __forceinline__ float bflo_(unsigned u) { return __uint_as_float(u << 16); }
__device__ __forceinline__ float bfhi_(unsigned u) { return __uint_as_float(u & 0xffff0000u); }

// ---- packed f32 pairs via NATIVE vector ops (compiler emits v_pk_*_f32) ----
__device__ __forceinline__ f32x2 pk_fma(f32x2 a, f32x2 b, f32x2 c) {
  return __builtin_elementwise_fma(a, b, c);
}
__device__ __forceinline__ f32x2 mk2(float a, float b) { return (f32x2){a, b}; }
__device__ __forceinline__ f32x2 bc2(float a) { return (f32x2){a, a}; }

__device__ __forceinline__ f32x2 silu2_(f32x2 p) {
  f32x2 np = -p;
  f32x2 e;
  e.x = __expf(np.x);
  e.y = __expf(np.y);
  f32x2 den = e + bc2(1.f);
  f32x2 r;
  r.x = __builtin_amdgcn_rcpf(den.x);
  r.y = __builtin_amdgcn_rcpf(den.y);
  return p * r;
}

// ---------------- prep kernel ----------------
__global__ __launch_bounds__(128) void prep_kernel(
    const float* __restrict__ sf, const float* __restrict__ cons,
    const float* __restrict__ eW1, const float* __restrict__ eb1,
    const float* __restrict__ eW2, const float* __restrict__ eb2,
    const float* __restrict__ vW1, const float* __restrict__ vb1,
    float* __restrict__ Ag, float* __restrict__ Bvg,
    unsigned short* __restrict__ E2V1T, float* __restrict__ m2,
    float* __restrict__ c1, float* __restrict__ mb)
{
  const int bid = blockIdx.x;
  const int d = threadIdx.x;
  if (bid < NODES) {
    float c = cons[bid];
    float aacc = c * eW1[258*DD + d];
    float bacc = eb1[d] + c * eW1[257*DD + d];
    const float* sfrow = sf + bid*DD;
    #pragma unroll 4
    for (int k = 0; k < DD; ++k) {
      float s = sfrow[k];
      aacc = fmaf(s, eW1[(128+k)*DD + d], aacc);
      bacc = fmaf(s, eW1[k*DD + d], bacc);
    }
    Ag[bid*DD + d]  = aacc;
    Bvg[bid*DD + d] = bacc;
  } else if (bid < NODES + 128) {
    // E2V1T[d][k^swz] = sum_t eW2[k,t]*vW1[t,d]  (bf16, pre-swizzled)
    const int k = bid - NODES;
    float acc = 0.f;
    #pragma unroll 4
    for (int t = 0; t < DD; ++t) acc = fmaf(eW2[k*DD + t], vW1[t*DD + d], acc);
    E2V1T[d*DD + (k ^ ((d & 7) << 3))] = f2bf_(acc);
    if (d == 0) {
      float s = 0.f;
      for (int t = 0; t < DD; ++t) s += eW2[k*DD + t];
      m2[k] = s * (1.0f/128.0f);
    }
  } else {
    float acc = vb1[d];
    #pragma unroll 4
    for (int k = 0; k < DD; ++k) acc = fmaf(eb2[k], vW1[k*DD + d], acc);
    c1[d] = acc;
    if (d == 0) {
      float s = 0.f;
      for (int k = 0; k < DD; ++k) s += eb2[k];
      mb[0] = s * (1.0f/128.0f);
    }
  }
}

// ---------------- main kernel: one block per (b,i); 2 rows/lane, t-loop unrolled 2x ----------------
__global__ __launch_bounds__(256, 2) void edge_kernel(
    const float* __restrict__ sf, const float* __restrict__ vf,
    const float* __restrict__ pos, const float* __restrict__ pm,
    const float* __restrict__ eW1,
    const float* __restrict__ eW2, const float* __restrict__ eb2,
    const float* __restrict__ sW1, const float* __restrict__ sb1,
    const float* __restrict__ sW2, const float* __restrict__ sb2,
    const float* __restrict__ vW2g, const float* __restrict__ vb2g,
    const float* __restrict__ lnw, const float* __restrict__ lnb,
    const float* __restrict__ Ag, const float* __restrict__ Bvg,
    const unsigned short* __restrict__ E2V1Tg, const float* __restrict__ m2g,
    const float* __restrict__ c1g, const float* __restrict__ mbg,
    float* __restrict__ sout, float* __restrict__ vout, float* __restrict__ ewout)
{
  __shared__ __align__(16) unsigned short eTs[128*128];   // 32 KB
  __shared__ __align__(16) float BvL[DD], w256L[DD], w259L[DD], m2L[DD];
  __shared__ __align__(16) float c1L[DD], vw2L[DD];
  __shared__ __align__(16) float scr2[1152];
  __shared__ float redS[4], redVx[4], redVy[4], redVz[4], redA[2], redB[2];

  const int tid = threadIdx.x;
  const int ni  = blockIdx.x;
  const int nb  = ni & ~(NN - 1);

  const int l   = tid & 63, w = tid >> 6;
  const int l15 = l & 15,  lg = l >> 4;
  const int d   = tid & 127, sub = tid >> 7;
  const int d0base = lg*8;

  // stage E2V1 (pre-swizzled bf16) into LDS
  {
    const uint4* src = (const uint4*)E2V1Tg;
    uint4* dst = (uint4*)eTs;
    #pragma unroll
    for (int it = 0; it < 8; ++it) dst[tid + it*256] = src[tid + it*256];
  }
  if (tid < 128) {
    BvL[tid]   = Bvg[(size_t)ni*DD + tid];
    w256L[tid] = eW1[256*DD + tid];
    w259L[tid] = eW1[259*DD + tid];
    m2L[tid]   = m2g[tid];
    c1L[tid]   = c1g[tid];
    vw2L[tid]  = vW2g[tid];
  }
  const float pix = pos[ni*3+0], piy = pos[ni*3+1], piz = pos[ni*3+2];
  const float mbv = mbg[0], vb2v = vb2g[0];

  f32x2 Sp[4][4];
  #pragma unroll
  for (int kk = 0; kk < 4; ++kk)
    #pragma unroll
    for (int m = 0; m < 4; ++m) Sp[kk][m] = (f32x2){0.f, 0.f};
  float vmx = 0.f, vmy = 0.f, vmz = 0.f, swacc = 0.f;

  __syncthreads();

  #pragma unroll 2
  for (int t = 0; t < 4; ++t) {
    const int row0 = t*128 + w*16 + l15;
    const int row1 = row0 + 64;
    float p0x = pos[(nb + row0)*3 + 0], p0y = pos[(nb + row0)*3 + 1], p0z = pos[(nb + row0)*3 + 2];
    float p1x = pos[(nb + row1)*3 + 0], p1y = pos[(nb + row1)*3 + 1], p1z = pos[(nb + row1)*3 + 2];
    float r0x = pix - p0x, r0y = piy - p0y, r0z = piz - p0z;
    float r1x = pix - p1x, r1y = piy - p1y, r1z = piz - p1z;
    float dist0 = fmaxf(sqrtf(r0x*r0x + r0y*r0y + r0z*r0z), 1e-8f);
    float dist1 = fmaxf(sqrtf(r1x*r1x + r1y*r1y + r1z*r1z), 1e-8f);
    float inv0 = __builtin_amdgcn_rcpf(dist0);
    float inv1 = __builtin_amdgcn_rcpf(dist1);
    float dir0x = r0x*inv0, dir0y = r0y*inv0, dir0z = r0z*inv0;
    float dir1x = r1x*inv1, dir1y = r1y*inv1, dir1z = r1z*inv1;
    float mj0 = pm[(size_t)ni*NN + row0];
    float mj1 = pm[(size_t)ni*NN + row1];

    const f32x2 distp0 = bc2(dist0), distp1 = bc2(dist1);
    const f32x2 mjp0 = bc2(mj0), mjp1 = bc2(mj1);

    uint4 pkA0, pkA1, pkA2, pkA3, pkB0, pkB1, pkB2, pkB3;
    f32x2 dotp0 = {0.f,0.f}, dotp1 = {0.f,0.f};
    const float* ag0 = Ag + (size_t)(nb + row0)*DD;
    const float* ag1 = Ag + (size_t)(nb + row1)*DD;

#define H_PAIR(BP, WAP, WBP, AP, DISTP, MJP) \
    silu2_(pk_fma(MJP, WBP, pk_fma(DISTP, WAP, (BP) + (AP))))

#define A_STEP2(KK, PKA, PKB) {                                                   \
    const int d0 = (KK)*32 + d0base;                                              \
    float4 b0 = *(const float4*)&BvL[d0],   b1 = *(const float4*)&BvL[d0+4];      \
    float4 wa0= *(const float4*)&w256L[d0], wa1= *(const float4*)&w256L[d0+4];    \
    float4 wb0= *(const float4*)&w259L[d0], wb1= *(const float4*)&w259L[d0+4];    \
    float4 m20= *(const float4*)&m2L[d0],   m21= *(const float4*)&m2L[d0+4];      \
    float4 aa0 = *(const float4*)(ag0 + d0), aa1 = *(const float4*)(ag0 + d0 + 4);\
    float4 ba0 = *(const float4*)(ag1 + d0), ba1 = *(const float4*)(ag1 + d0 + 4);\
    f32x2 hA0 = H_PAIR(mk2(b0.x,b0.y), mk2(wa0.x,wa0.y), mk2(wb0.x,wb0.y), mk2(aa0.x,aa0.y), distp0, mjp0); \
    f32x2 hA1 = H_PAIR(mk2(b0.z,b0.w), mk2(wa0.z,wa0.w), mk2(wb0.z,wb0.w), mk2(aa0.z,aa0.w), distp0, mjp0); \
    f32x2 hA2 = H_PAIR(mk2(b1.x,b1.y), mk2(wa1.x,wa1.y), mk2(wb1.x,wb1.y), mk2(aa1.x,aa1.y), distp0, mjp0); \
    f32x2 hA3 = H_PAIR(mk2(b1.z,b1.w), mk2(wa1.z,wa1.w), mk2(wb1.z,wb1.w), mk2(aa1.z,aa1.w), distp0, mjp0); \
    f32x2 hB0 = H_PAIR(mk2(b0.x,b0.y), mk2(wa0.x,wa0.y), mk2(wb0.x,wb0.y), mk2(ba0.x,ba0.y), distp1, mjp1); \
    f32x2 hB1 = H_PAIR(mk2(b0.z,b0.w), mk2(wa0.z,wa0.w), mk2(wb0.z,wb0.w), mk2(ba0.z,ba0.w), distp1, mjp1); \
    f32x2 hB2 = H_PAIR(mk2(b1.x,b1.y), mk2(wa1.x,wa1.y), mk2(wb1.x,wb1.y), mk2(ba1.x,ba1.y), distp1, mjp1); \
    f32x2 hB3 = H_PAIR(mk2(b1.z,b1.w), mk2(wa1.z,wa1.w), mk2(wb1.z,wb1.w), mk2(ba1.z,ba1.w), distp1, mjp1); \
    PKA.x = cvtpk_(hA0.x, hA0.y); PKA.y = cvtpk_(hA1.x, hA1.y);                   \
    PKA.z = cvtpk_(hA2.x, hA2.y); PKA.w = cvtpk_(hA3.x, hA3.y);                   \
    PKB.x = cvtpk_(hB0.x, hB0.y); PKB.y = cvtpk_(hB1.x, hB1.y);                   \
    PKB.z = cvtpk_(hB2.x, hB2.y); PKB.w = cvtpk_(hB3.x, hB3.y);                   \
    dotp0 = pk_fma(hA0, mk2(m20.x,m20.y), dotp0);                                 \
    dotp0 = pk_fma(hA1, mk2(m20.z,m20.w), dotp0);                                 \
    dotp0 = pk_fma(hA2, mk2(m21.x,m21.y), dotp0);                                 \
    dotp0 = pk_fma(hA3, mk2(m21.z,m21.w), dotp0);                                 \
    dotp1 = pk_fma(hB0, mk2(m20.x,m20.y), dotp1);                                 \
    dotp1 = pk_fma(hB1, mk2(m20.z,m20.w), dotp1);                                 \
    dotp1 = pk_fma(hB2, mk2(m21.x,m21.y), dotp1);                                 \
    dotp1 = pk_fma(hB3, mk2(m21.z,m21.w), dotp1); }

    A_STEP2(0, pkA0, pkB0)
    A_STEP2(1, pkA1, pkB1)
    A_STEP2(2, pkA2, pkB2)
    A_STEP2(3, pkA3, pkB3)
#undef A_STEP2
#undef H_PAIR

    float dot0 = dotp0.x + dotp0.y;
    float dot1 = dotp1.x + dotp1.y;
    dot0 += __shfl_xor(dot0, 16);
    dot0 += __shfl_xor(dot0, 32);
    dot1 += __shfl_xor(dot1, 16);
    dot1 += __shfl_xor(dot1, 32);
    const float w0 = mj0 * sigmoidf_(dot0 + mbv);
    const float w1 = mj1 * sigmoidf_(dot1 + mbv);
    if (lg == 0) {
      ewout[(size_t)ni*NN + row0] = w0;
      ewout[(size_t)ni*NN + row1] = w1;
      swacc += w0 + w1;
    }
    const f32x2 w0p = bc2(w0), w1p = bc2(w1);

#define S_STEP2(KK, PKA, PKB) {                                                     \
    Sp[KK][0] = pk_fma(w1p, mk2(bflo_(PKB.x), bfhi_(PKB.x)),                        \
                pk_fma(w0p, mk2(bflo_(PKA.x), bfhi_(PKA.x)), Sp[KK][0]));           \
    Sp[KK][1] = pk_fma(w1p, mk2(bflo_(PKB.y), bfhi_(PKB.y)),                        \
                pk_fma(w0p, mk2(bflo_(PKA.y), bfhi_(PKA.y)), Sp[KK][1]));           \
    Sp[KK][2] = pk_fma(w1p, mk2(bflo_(PKB.z), bfhi_(PKB.z)),                        \
                pk_fma(w0p, mk2(bflo_(PKA.z), bfhi_(PKA.z)), Sp[KK][2]));           \
    Sp[KK][3] = pk_fma(w1p, mk2(bflo_(PKB.w), bfhi_(PKB.w)),                        \
                pk_fma(w0p, mk2(bflo_(PKA.w), bfhi_(PKA.w)), Sp[KK][3])); }

    S_STEP2(0, pkA0, pkB0)
    S_STEP2(1, pkA1, pkB1)
    S_STEP2(2, pkA2, pkB2)
    S_STEP2(3, pkA3, pkB3)
#undef S_STEP2

    const bf16x8 afA0 = __builtin_bit_cast(bf16x8, pkA0);
    const bf16x8 afA1 = __builtin_bit_cast(bf16x8, pkA1);
    const bf16x8 afA2 = __builtin_bit_cast(bf16x8, pkA2);
    const bf16x8 afA3 = __builtin_bit_cast(bf16x8, pkA3);
    const bf16x8 afB0 = __builtin_bit_cast(bf16x8, pkB0);
    const bf16x8 afB1 = __builtin_bit_cast(bf16x8, pkB1);
    const bf16x8 afB2 = __builtin_bit_cast(bf16x8, pkB2);
    const bf16x8 afB3 = __builtin_bit_cast(bf16x8, pkB3);

    // ---- B: MFMA over 128 cols; gate silu on pairs ----
    f32x2 gp0a = {0.f,0.f}, gp0b = {0.f,0.f};
    f32x2 gp1a = {0.f,0.f}, gp1b = {0.f,0.f};
    #pragma unroll
    for (int ct = 0; ct < 8; ++ct) {
      const int col = ct*16 + l15;
      const int swz = (col & 7) << 3;
      const unsigned short* ecol = &eTs[col*DD];
      bf16x8 bf0 = *(const bf16x8*)&ecol[(  0 + d0base) ^ swz];
      bf16x8 bf1 = *(const bf16x8*)&ecol[( 32 + d0base) ^ swz];
      bf16x8 bf2 = *(const bf16x8*)&ecol[( 64 + d0base) ^ swz];
      bf16x8 bf3 = *(const bf16x8*)&ecol[( 96 + d0base) ^ swz];
      f32x4 c0 = {0.f,0.f,0.f,0.f};
      f32x4 c1v = {0.f,0.f,0.f,0.f};
      c0  = __builtin_amdgcn_mfma_f32_16x16x32_bf16(afA0, bf0, c0, 0, 0, 0);
      c1v = __builtin_amdgcn_mfma_f32_16x16x32_bf16(afB0, bf0, c1v, 0, 0, 0);
      c0  = __builtin_amdgcn_mfma_f32_16x16x32_bf16(afA1, bf1, c0, 0, 0, 0);
      c1v = __builtin_amdgcn_mfma_f32_16x16x32_bf16(afB1, bf1, c1v, 0, 0, 0);
      c0  = __builtin_amdgcn_mfma_f32_16x16x32_bf16(afA2, bf2, c0, 0, 0, 0);
      c1v = __builtin_amdgcn_mfma_f32_16x16x32_bf16(afB2, bf2, c1v, 0, 0, 0);
      c0  = __builtin_amdgcn_mfma_f32_16x16x32_bf16(afA3, bf3, c0, 0, 0, 0);
      c1v = __builtin_amdgcn_mfma_f32_16x16x32_bf16(afB3, bf3, c1v, 0, 0, 0);
      const f32x2 c1p = bc2(c1L[col]);
      const f32x2 vwp = bc2(vw2L[col]);
      gp0a = pk_fma(silu2_(mk2(c0[0],  c0[1])  + c1p), vwp, gp0a);
      gp0b = pk_fma(silu2_(mk2(c0[2],  c0[3])  + c1p), vwp, gp0b);
      gp1a = pk_fma(silu2_(mk2(c1v[0], c1v[1]) + c1p), vwp, gp1a);
      gp1b = pk_fma(silu2_(mk2(c1v[2], c1v[3]) + c1p), vwp, gp1b);
    }
    {
      float g4_0[4] = { gp0a.x, gp0a.y, gp0b.x, gp0b.y };
      float g4_1[4] = { gp1a.x, gp1a.y, gp1b.x, gp1b.y };
      #pragma unroll
      for (int r = 0; r < 4; ++r) {
        float v0 = g4_0[r], v1 = g4_1[r];
        v0 += __shfl_xor(v0, 1);  v1 += __shfl_xor(v1, 1);
        v0 += __shfl_xor(v0, 2);  v1 += __shfl_xor(v1, 2);
        v0 += __shfl_xor(v0, 4);  v1 += __shfl_xor(v1, 4);
        v0 += __shfl_xor(v0, 8);  v1 += __shfl_xor(v1, 8);
        const int srow = lg*4 + r;
        float wr0 = __shfl(w0, srow);
        float wr1 = __shfl(w1, srow);
        float g0 = (v0 + vb2v) * wr0;
        float g1 = (v1 + vb2v) * wr1;
        float d0x = __shfl(dir0x, srow), d0y = __shfl(dir0y, srow), d0z = __shfl(dir0z, srow);
        float d1x = __shfl(dir1x, srow), d1y = __shfl(dir1y, srow), d1z = __shfl(dir1z, srow);
        if (l15 == 0) {
          vmx = fmaf(g0, d0x, fmaf(g1, d1x, vmx));
          vmy = fmaf(g0, d0y, fmaf(g1, d1y, vmy));
          vmz = fmaf(g0, d0z, fmaf(g1, d1z, vmz));
        }
      }
    }
  }

  // -------- epilogue --------
  float* Spart = scr2;             // [4][128]
  float* SL    = scr2 + 512;
  float* partA = scr2 + 640;
  float* msgL  = scr2 + 768;
  float* u1L   = scr2 + 896;
  float* xoL   = scr2 + 1024;

  #pragma unroll
  for (int kk = 0; kk < 4; ++kk)
    #pragma unroll
    for (int m = 0; m < 4; ++m) {
      float va = Sp[kk][m].x, vb = Sp[kk][m].y;
      va += __shfl_xor(va, 1);  vb += __shfl_xor(vb, 1);
      va += __shfl_xor(va, 2);  vb += __shfl_xor(vb, 2);
      va += __shfl_xor(va, 4);  vb += __shfl_xor(vb, 4);
      va += __shfl_xor(va, 8);  vb += __shfl_xor(vb, 8);
      Sp[kk][m].x = va; Sp[kk][m].y = vb;
    }
  if (l15 == 0) {
    #pragma unroll
    for (int kk = 0; kk < 4; ++kk)
      #pragma unroll
      for (int m = 0; m < 4; ++m) {
        Spart[w*128 + kk*32 + lg*8 + m*2 + 0] = Sp[kk][m].x;
        Spart[w*128 + kk*32 + lg*8 + m*2 + 1] = Sp[kk][m].y;
      }
  }
  {
    float sw = swacc;
    #pragma unroll
    for (int off = 1; off < 64; off <<= 1) sw += __shfl_xor(sw, off);
    if (l == 0) redS[w] = sw;
  }
  {
    float vx = vmx, vy = vmy, vz = vmz;
    #pragma unroll
    for (int off = 1; off < 64; off <<= 1) {
      vx += __shfl_xor(vx, off);
      vy += __shfl_xor(vy, off);
      vz += __shfl_xor(vz, off);
    }
    if (l == 0) { redVx[w] = vx; redVy[w] = vy; redVz[w] = vz; }
  }
  __syncthreads();
  if (tid < 128) SL[tid] = Spart[tid] + Spart[128+tid] + Spart[256+tid] + Spart[384+tid];
  if (tid == 0) {
    vout[ni*3 + 0] = vf[ni*3 + 0] + redVx[0]+redVx[1]+redVx[2]+redVx[3];
    vout[ni*3 + 1] = vf[ni*3 + 1] + redVy[0]+redVy[1]+redVy[2]+redVy[3];
    vout[ni*3 + 2] = vf[ni*3 + 2] + redVz[0]+redVz[1]+redVz[2]+redVz[3];
  }
  __syncthreads();
  const float sumwv = redS[0] + redS[1] + redS[2] + redS[3];

  // message_scalar = S@eW2 + sumw*eb2  (dual accumulators)
  float p = 0.f;
  { int k0 = sub*64;
    float pa = 0.f, pb = 0.f;
    #pragma unroll 4
    for (int k = k0; k < k0 + 32; ++k) {
      pa = fmaf(SL[k], eW2[k*DD + d], pa);
      pb = fmaf(SL[k+32], eW2[(k+32)*DD + d], pb);
    }
    p = pa + pb; }
  if (sub) partA[d] = p;
  __syncthreads();
  if (!sub) msgL[d] = p + partA[d] + sumwv * eb2[d];
  __syncthreads();

  // u1 = silu([x, msg] @ sW1 + sb1)
  float q = 0.f;
  if (!sub) {
    const float* xr = sf + (size_t)ni*DD;
    float qa = 0.f, qb = 0.f;
    #pragma unroll 4
    for (int tt = 0; tt < 64; ++tt) {
      qa = fmaf(xr[tt], sW1[tt*DD + d], qa);
      qb = fmaf(xr[tt+64], sW1[(tt+64)*DD + d], qb);
    }
    q = qa + qb;
  } else {
    float qa = 0.f, qb = 0.f;
    #pragma unroll 4
    for (int tt = 0; tt < 64; ++tt) {
      qa = fmaf(msgL[tt], sW1[(128 + tt)*DD + d], qa);
      qb = fmaf(msgL[tt+64], sW1[(192 + tt)*DD + d], qb);
    }
    q = qa + qb;
  }
  if (sub) partA[d] = q;
  __syncthreads();
  if (!sub) u1L[d] = siluf_(q + partA[d] + sb1[d]);
  __syncthreads();

  // upd = u1 @ sW2 + sb2; x = sf + upd
  float r2 = 0.f;
  { int t0 = sub*64;
    float ra = 0.f, rb = 0.f;
    #pragma unroll 4
    for (int tt = t0; tt < t0 + 32; ++tt) {
      ra = fmaf(u1L[tt], sW2[tt*DD + d], ra);
      rb = fmaf(u1L[tt+32], sW2[(tt+32)*DD + d], rb);
    }
    r2 = ra + rb; }
  if (sub) partA[d] = r2;
  __syncthreads();
  if (!sub) xoL[d] = sf[(size_t)ni*DD + d] + r2 + partA[d] + sb2[d];
  __syncthreads();

  // LayerNorm
  if (tid < 128) {
    float v = xoL[tid];
    float s1 = v, s2 = v*v;
    #pragma unroll
    for (int off = 1; off < 64; off <<= 1) { s1 += __shfl_xor(s1, off); s2 += __shfl_xor(s2, off); }
    if ((tid & 63) == 0) { redA[tid >> 6] = s1; redB[tid >> 6] = s2; }
  }
  __syncthreads();
  if (tid < 128) {
    float s1 = redA[0] + redA[1], s2 = redB[0] + redB[1];
    float mu = s1 * 0.0078125f;
    float var = s2 * 0.0078125f - mu*mu;
    sout[(size_t)ni*DD + tid] = (xoL[tid] - mu) * rsqrtf(var + 1e-5f) * lnw[tid] + lnb[tid];
  }
}

extern "C" void kernel_launch(void* const* d_in, const int* in_sizes, int n_in,
                              void* d_out, int out_size, void* d_ws, size_t ws_size,
                              hipStream_t stream) {
  const float* sf   = (const float*)d_in[0];
  const float* vf   = (const float*)d_in[1];
  const float* pos  = (const float*)d_in[2];
  const float* pm   = (const float*)d_in[3];
  const float* cons = (const float*)d_in[4];
  const float* eW1  = (const float*)d_in[5];
  const float* eb1  = (const float*)d_in[6];
  const float* eW2  = (const float*)d_in[7];
  const float* eb2  = (const float*)d_in[8];
  const float* sW1  = (const float*)d_in[9];
  const float* sb1  = (const float*)d_in[10];
  const float* sW2  = (const float*)d_in[11];
  const float* sb2  = (const float*)d_in[12];
  const float* vW1  = (const float*)d_in[13];
  const float* vb1  = (const float*)d_in[14];
  const float* vW2  = (const float*)d_in[15];
  const float* vb2  = (const float*)d_in[16];
  const float* lnw  = (const float*)d_in[17];
  const float* lnb  = (const float*)d_in[18];

  float* ws   = (float*)d_ws;
  float* Ag   = ws;                              // 1024*128 f32
  float* Bvg  = ws + 131072;                     // 1024*128 f32
  float* m2   = ws + 262144;                     // 128
  float* c1   = ws + 262272;                     // 128
  float* mb   = ws + 262400;                     // 1 (+pad)
  unsigned short* E2V1T = (unsigned short*)(ws + 262404); // 128*128 bf16, 16B-aligned

  float* sout  = (float*)d_out;      // [2,512,128]
  float* vout  = sout + 131072;      // [2,512,3]
  float* ewout = sout + 134144;      // [2,512,512]

  hipLaunchKernelGGL(prep_kernel, dim3(NODES + 129), dim3(128), 0, stream,
                     sf, cons, eW1, eb1, eW2, eb2, vW1, vb1,
                     Ag, Bvg, E2V1T, m2, c1, mb);
  hipLaunchKernelGGL(edge_kernel, dim3(NODES), dim3(256), 0, stream,
                     sf, vf, pos, pm, eW1, eW2, eb2, sW1, sb1, sW2, sb2,
                     vW2, vb2, lnw, lnb, Ag, Bvg, E2V1T, m2, c1, mb,
                     sout, vout, ewout);
}

// Round 14
// 155.035 us; speedup vs baseline: 1.4362x; 1.4362x over previous
//
#include <hip/hip_runtime.h>

#define DD 128
#define NN 512
#define NODES 1024

typedef short bf16x8 __attribute__((ext_vector_type(8)));
typedef float f32x4 __attribute__((ext_vector_type(4)));
typedef float f32x2 __attribute__((ext_vector_type(2)));

__device__ __forceinline__ float sigmoidf_(float x) {
  return __builtin_amdgcn_rcpf(1.f + __expf(-x));
}
__device__ __forceinline__ float siluf_(float x) { return x * sigmoidf_(x); }

__device__ __forceinline__ unsigned short f2bf_(float v) {
  unsigned int u = __float_as_uint(v);
  u += 0x7fffu + ((u >> 16) & 1u);   // RNE
  return (unsigned short)(u >> 16);
}
__device__ __forceinline__ unsigned cvtpk_(float lo, float hi) {
  unsigned r;
  asm("v_cvt_pk_bf16_f32 %0, %1, %2" : "=v"(r) : "v"(lo), "v"(hi));
  return r;
}
__device__ __forceinline__ float bflo_(unsigned u) { return __uint_as_float(u << 16); }
__device__ __forceinline__ float bfhi_(unsigned u) { return __uint_as_float(u & 0xffff0000u); }

// ---- packed f32 pairs via NATIVE vector ops (compiler emits v_pk_*_f32) ----
__device__ __forceinline__ f32x2 pk_fma(f32x2 a, f32x2 b, f32x2 c) {
  return __builtin_elementwise_fma(a, b, c);
}
__device__ __forceinline__ f32x2 mk2(float a, float b) { return (f32x2){a, b}; }
__device__ __forceinline__ f32x2 bc2(float a) { return (f32x2){a, a}; }

__device__ __forceinline__ f32x2 silu2_(f32x2 p) {
  f32x2 np = -p;
  f32x2 e;
  e.x = __expf(np.x);
  e.y = __expf(np.y);
  f32x2 den = e + bc2(1.f);
  f32x2 r;
  r.x = __builtin_amdgcn_rcpf(den.x);
  r.y = __builtin_amdgcn_rcpf(den.y);
  return p * r;
}

// ---------------- prep kernel ----------------
__global__ __launch_bounds__(128) void prep_kernel(
    const float* __restrict__ sf, const float* __restrict__ cons,
    const float* __restrict__ eW1, const float* __restrict__ eb1,
    const float* __restrict__ eW2, const float* __restrict__ eb2,
    const float* __restrict__ vW1, const float* __restrict__ vb1,
    float* __restrict__ Ag, float* __restrict__ Bvg,
    unsigned short* __restrict__ E2V1T, float* __restrict__ m2,
    float* __restrict__ c1, float* __restrict__ mb)
{
  const int bid = blockIdx.x;
  const int d = threadIdx.x;
  if (bid < NODES) {
    float c = cons[bid];
    float aacc = c * eW1[258*DD + d];
    float bacc = eb1[d] + c * eW1[257*DD + d];
    const float* sfrow = sf + bid*DD;
    #pragma unroll 4
    for (int k = 0; k < DD; ++k) {
      float s = sfrow[k];
      aacc = fmaf(s, eW1[(128+k)*DD + d], aacc);
      bacc = fmaf(s, eW1[k*DD + d], bacc);
    }
    Ag[bid*DD + d]  = aacc;
    Bvg[bid*DD + d] = bacc;
  } else if (bid < NODES + 128) {
    // E2V1T[d][k^swz] = sum_t eW2[k,t]*vW1[t,d]  (bf16, pre-swizzled)
    const int k = bid - NODES;
    float acc = 0.f;
    #pragma unroll 4
    for (int t = 0; t < DD; ++t) acc = fmaf(eW2[k*DD + t], vW1[t*DD + d], acc);
    E2V1T[d*DD + (k ^ ((d & 7) << 3))] = f2bf_(acc);
    if (d == 0) {
      float s = 0.f;
      for (int t = 0; t < DD; ++t) s += eW2[k*DD + t];
      m2[k] = s * (1.0f/128.0f);
    }
  } else {
    float acc = vb1[d];
    #pragma unroll 4
    for (int k = 0; k < DD; ++k) acc = fmaf(eb2[k], vW1[k*DD + d], acc);
    c1[d] = acc;
    if (d == 0) {
      float s = 0.f;
      for (int k = 0; k < DD; ++k) s += eb2[k];
      mb[0] = s * (1.0f/128.0f);
    }
  }
}

// ---------------- main kernel: one block per (b,i); 2 rows/lane, t-loop unrolled 2x ----------------
__global__ __launch_bounds__(256, 1) void edge_kernel(
    const float* __restrict__ sf, const float* __restrict__ vf,
    const float* __restrict__ pos, const float* __restrict__ pm,
    const float* __restrict__ eW1,
    const float* __restrict__ eW2, const float* __restrict__ eb2,
    const float* __restrict__ sW1, const float* __restrict__ sb1,
    const float* __restrict__ sW2, const float* __restrict__ sb2,
    const float* __restrict__ vW2g, const float* __restrict__ vb2g,
    const float* __restrict__ lnw, const float* __restrict__ lnb,
    const float* __restrict__ Ag, const float* __restrict__ Bvg,
    const unsigned short* __restrict__ E2V1Tg, const float* __restrict__ m2g,
    const float* __restrict__ c1g, const float* __restrict__ mbg,
    float* __restrict__ sout, float* __restrict__ vout, float* __restrict__ ewout)
{
  __shared__ __align__(16) unsigned short eTs[128*128];   // 32 KB
  __shared__ __align__(16) float BvL[DD], w256L[DD], w259L[DD], m2L[DD];
  __shared__ __align__(16) float c1L[DD], vw2L[DD];
  __shared__ __align__(16) float scr2[1152];
  __shared__ float redS[4], redVx[4], redVy[4], redVz[4], redA[2], redB[2];

  const int tid = threadIdx.x;
  const int ni  = blockIdx.x;
  const int nb  = ni & ~(NN - 1);

  const int l   = tid & 63, w = tid >> 6;
  const int l15 = l & 15,  lg = l >> 4;
  const int d   = tid & 127, sub = tid >> 7;
  const int d0base = lg*8;

  // stage E2V1 (pre-swizzled bf16) into LDS
  {
    const uint4* src = (const uint4*)E2V1Tg;
    uint4* dst = (uint4*)eTs;
    #pragma unroll
    for (int it = 0; it < 8; ++it) dst[tid + it*256] = src[tid + it*256];
  }
  if (tid < 128) {
    BvL[tid]   = Bvg[(size_t)ni*DD + tid];
    w256L[tid] = eW1[256*DD + tid];
    w259L[tid] = eW1[259*DD + tid];
    m2L[tid]   = m2g[tid];
    c1L[tid]   = c1g[tid];
    vw2L[tid]  = vW2g[tid];
  }
  const float pix = pos[ni*3+0], piy = pos[ni*3+1], piz = pos[ni*3+2];
  const float mbv = mbg[0], vb2v = vb2g[0];

  f32x2 Sp[4][4];
  #pragma unroll
  for (int kk = 0; kk < 4; ++kk)
    #pragma unroll
    for (int m = 0; m < 4; ++m) Sp[kk][m] = (f32x2){0.f, 0.f};
  float vmx = 0.f, vmy = 0.f, vmz = 0.f, swacc = 0.f;

  __syncthreads();

  #pragma unroll 2
  for (int t = 0; t < 4; ++t) {
    const int row0 = t*128 + w*16 + l15;
    const int row1 = row0 + 64;
    float p0x = pos[(nb + row0)*3 + 0], p0y = pos[(nb + row0)*3 + 1], p0z = pos[(nb + row0)*3 + 2];
    float p1x = pos[(nb + row1)*3 + 0], p1y = pos[(nb + row1)*3 + 1], p1z = pos[(nb + row1)*3 + 2];
    float r0x = pix - p0x, r0y = piy - p0y, r0z = piz - p0z;
    float r1x = pix - p1x, r1y = piy - p1y, r1z = piz - p1z;
    float dist0 = fmaxf(sqrtf(r0x*r0x + r0y*r0y + r0z*r0z), 1e-8f);
    float dist1 = fmaxf(sqrtf(r1x*r1x + r1y*r1y + r1z*r1z), 1e-8f);
    float inv0 = __builtin_amdgcn_rcpf(dist0);
    float inv1 = __builtin_amdgcn_rcpf(dist1);
    float dir0x = r0x*inv0, dir0y = r0y*inv0, dir0z = r0z*inv0;
    float dir1x = r1x*inv1, dir1y = r1y*inv1, dir1z = r1z*inv1;
    float mj0 = pm[(size_t)ni*NN + row0];
    float mj1 = pm[(size_t)ni*NN + row1];

    const f32x2 distp0 = bc2(dist0), distp1 = bc2(dist1);
    const f32x2 mjp0 = bc2(mj0), mjp1 = bc2(mj1);

    uint4 pkA0, pkA1, pkA2, pkA3, pkB0, pkB1, pkB2, pkB3;
    f32x2 dotp0 = {0.f,0.f}, dotp1 = {0.f,0.f};
    const float* ag0 = Ag + (size_t)(nb + row0)*DD;
    const float* ag1 = Ag + (size_t)(nb + row1)*DD;

#define H_PAIR(BP, WAP, WBP, AP, DISTP, MJP) \
    silu2_(pk_fma(MJP, WBP, pk_fma(DISTP, WAP, (BP) + (AP))))

#define A_STEP2(KK, PKA, PKB) {                                                   \
    const int d0 = (KK)*32 + d0base;                                              \
    float4 b0 = *(const float4*)&BvL[d0],   b1 = *(const float4*)&BvL[d0+4];      \
    float4 wa0= *(const float4*)&w256L[d0], wa1= *(const float4*)&w256L[d0+4];    \
    float4 wb0= *(const float4*)&w259L[d0], wb1= *(const float4*)&w259L[d0+4];    \
    float4 m20= *(const float4*)&m2L[d0],   m21= *(const float4*)&m2L[d0+4];      \
    float4 aa0 = *(const float4*)(ag0 + d0), aa1 = *(const float4*)(ag0 + d0 + 4);\
    float4 ba0 = *(const float4*)(ag1 + d0), ba1 = *(const float4*)(ag1 + d0 + 4);\
    f32x2 hA0 = H_PAIR(mk2(b0.x,b0.y), mk2(wa0.x,wa0.y), mk2(wb0.x,wb0.y), mk2(aa0.x,aa0.y), distp0, mjp0); \
    f32x2 hA1 = H_PAIR(mk2(b0.z,b0.w), mk2(wa0.z,wa0.w), mk2(wb0.z,wb0.w), mk2(aa0.z,aa0.w), distp0, mjp0); \
    f32x2 hA2 = H_PAIR(mk2(b1.x,b1.y), mk2(wa1.x,wa1.y), mk2(wb1.x,wb1.y), mk2(aa1.x,aa1.y), distp0, mjp0); \
    f32x2 hA3 = H_PAIR(mk2(b1.z,b1.w), mk2(wa1.z,wa1.w), mk2(wb1.z,wb1.w), mk2(aa1.z,aa1.w), distp0, mjp0); \
    f32x2 hB0 = H_PAIR(mk2(b0.x,b0.y), mk2(wa0.x,wa0.y), mk2(wb0.x,wb0.y), mk2(ba0.x,ba0.y), distp1, mjp1); \
    f32x2 hB1 = H_PAIR(mk2(b0.z,b0.w), mk2(wa0.z,wa0.w), mk2(wb0.z,wb0.w), mk2(ba0.z,ba0.w), distp1, mjp1); \
    f32x2 hB2 = H_PAIR(mk2(b1.x,b1.y), mk2(wa1.x,wa1.y), mk2(wb1.x,wb1.y), mk2(ba1.x,ba1.y), distp1, mjp1); \
    f32x2 hB3 = H_PAIR(mk2(b1.z,b1.w), mk2(wa1.z,wa1.w), mk2(wb1.z,wb1.w), mk2(ba1.z,ba1.w), distp1, mjp1); \
    PKA.x = cvtpk_(hA0.x, hA0.y); PKA.y = cvtpk_(hA1.x, hA1.y);                   \
    PKA.z = cvtpk_(hA2.x, hA2.y); PKA.w = cvtpk_(hA3.x, hA3.y);                   \
    PKB.x = cvtpk_(hB0.x, hB0.y); PKB.y = cvtpk_(hB1.x, hB1.y);                   \
    PKB.z = cvtpk_(hB2.x, hB2.y); PKB.w = cvtpk_(hB3.x, hB3.y);                   \
    dotp0 = pk_fma(hA0, mk2(m20.x,m20.y), dotp0);                                 \
    dotp0 = pk_fma(hA1, mk2(m20.z,m20.w), dotp0);                                 \
    dotp0 = pk_fma(hA2, mk2(m21.x,m21.y), dotp0);                                 \
    dotp0 = pk_fma(hA3, mk2(m21.z,m21.w), dotp0);                                 \
    dotp1 = pk_fma(hB0, mk2(m20.x,m20.y), dotp1);                                 \
    dotp1 = pk_fma(hB1, mk2(m20.z,m20.w), dotp1);                                 \
    dotp1 = pk_fma(hB2, mk2(m21.x,m21.y), dotp1);                                 \
    dotp1 = pk_fma(hB3, mk2(m21.z,m21.w), dotp1); }

    A_STEP2(0, pkA0, pkB0)
    A_STEP2(1, pkA1, pkB1)
    A_STEP2(2, pkA2, pkB2)
    A_STEP2(3, pkA3, pkB3)
#undef A_STEP2
#undef H_PAIR

    float dot0 = dotp0.x + dotp0.y;
    float dot1 = dotp1.x + dotp1.y;
    dot0 += __shfl_xor(dot0, 16);
    dot0 += __shfl_xor(dot0, 32);
    dot1 += __shfl_xor(dot1, 16);
    dot1 += __shfl_xor(dot1, 32);
    const float w0 = mj0 * sigmoidf_(dot0 + mbv);
    const float w1 = mj1 * sigmoidf_(dot1 + mbv);
    if (lg == 0) {
      ewout[(size_t)ni*NN + row0] = w0;
      ewout[(size_t)ni*NN + row1] = w1;
      swacc += w0 + w1;
    }
    const f32x2 w0p = bc2(w0), w1p = bc2(w1);

#define S_STEP2(KK, PKA, PKB) {                                                     \
    Sp[KK][0] = pk_fma(w1p, mk2(bflo_(PKB.x), bfhi_(PKB.x)),                        \
                pk_fma(w0p, mk2(bflo_(PKA.x), bfhi_(PKA.x)), Sp[KK][0]));           \
    Sp[KK][1] = pk_fma(w1p, mk2(bflo_(PKB.y), bfhi_(PKB.y)),                        \
                pk_fma(w0p, mk2(bflo_(PKA.y), bfhi_(PKA.y)), Sp[KK][1]));           \
    Sp[KK][2] = pk_fma(w1p, mk2(bflo_(PKB.z), bfhi_(PKB.z)),                        \
                pk_fma(w0p, mk2(bflo_(PKA.z), bfhi_(PKA.z)), Sp[KK][2]));           \
    Sp[KK][3] = pk_fma(w1p, mk2(bflo_(PKB.w), bfhi_(PKB.w)),                        \
                pk_fma(w0p, mk2(bflo_(PKA.w), bfhi_(PKA.w)), Sp[KK][3])); }

    S_STEP2(0, pkA0, pkB0)
    S_STEP2(1, pkA1, pkB1)
    S_STEP2(2, pkA2, pkB2)
    S_STEP2(3, pkA3, pkB3)
#undef S_STEP2

    const bf16x8 afA0 = __builtin_bit_cast(bf16x8, pkA0);
    const bf16x8 afA1 = __builtin_bit_cast(bf16x8, pkA1);
    const bf16x8 afA2 = __builtin_bit_cast(bf16x8, pkA2);
    const bf16x8 afA3 = __builtin_bit_cast(bf16x8, pkA3);
    const bf16x8 afB0 = __builtin_bit_cast(bf16x8, pkB0);
    const bf16x8 afB1 = __builtin_bit_cast(bf16x8, pkB1);
    const bf16x8 afB2 = __builtin_bit_cast(bf16x8, pkB2);
    const bf16x8 afB3 = __builtin_bit_cast(bf16x8, pkB3);

    // ---- B: MFMA over 128 cols; gate silu on pairs ----
    f32x2 gp0a = {0.f,0.f}, gp0b = {0.f,0.f};
    f32x2 gp1a = {0.f,0.f}, gp1b = {0.f,0.f};
    #pragma unroll
    for (int ct = 0; ct < 8; ++ct) {
      const int col = ct*16 + l15;
      const int swz = (col & 7) << 3;
      const unsigned short* ecol = &eTs[col*DD];
      bf16x8 bf0 = *(const bf16x8*)&ecol[(  0 + d0base) ^ swz];
      bf16x8 bf1 = *(const bf16x8*)&ecol[( 32 + d0base) ^ swz];
      bf16x8 bf2 = *(const bf16x8*)&ecol[( 64 + d0base) ^ swz];
      bf16x8 bf3 = *(const bf16x8*)&ecol[( 96 + d0base) ^ swz];
      f32x4 c0 = {0.f,0.f,0.f,0.f};
      f32x4 c1v = {0.f,0.f,0.f,0.f};
      c0  = __builtin_amdgcn_mfma_f32_16x16x32_bf16(afA0, bf0, c0, 0, 0, 0);
      c1v = __builtin_amdgcn_mfma_f32_16x16x32_bf16(afB0, bf0, c1v, 0, 0, 0);
      c0  = __builtin_amdgcn_mfma_f32_16x16x32_bf16(afA1, bf1, c0, 0, 0, 0);
      c1v = __builtin_amdgcn_mfma_f32_16x16x32_bf16(afB1, bf1, c1v, 0, 0, 0);
      c0  = __builtin_amdgcn_mfma_f32_16x16x32_bf16(afA2, bf2, c0, 0, 0, 0);
      c1v = __builtin_amdgcn_mfma_f32_16x16x32_bf16(afB2, bf2, c1v, 0, 0, 0);
      c0  = __builtin_amdgcn_mfma_f32_16x16x32_bf16(afA3, bf3, c0, 0, 0, 0);
      c1v = __builtin_amdgcn_mfma_f32_16x16x32_bf16(afB3, bf3, c1v, 0, 0, 0);
      const f32x2 c1p = bc2(c1L[col]);
      const f32x2 vwp = bc2(vw2L[col]);
      gp0a = pk_fma(silu2_(mk2(c0[0],  c0[1])  + c1p), vwp, gp0a);
      gp0b = pk_fma(silu2_(mk2(c0[2],  c0[3])  + c1p), vwp, gp0b);
      gp1a = pk_fma(silu2_(mk2(c1v[0], c1v[1]) + c1p), vwp, gp1a);
      gp1b = pk_fma(silu2_(mk2(c1v[2], c1v[3]) + c1p), vwp, gp1b);
    }
    {
      float g4_0[4] = { gp0a.x, gp0a.y, gp0b.x, gp0b.y };
      float g4_1[4] = { gp1a.x, gp1a.y, gp1b.x, gp1b.y };
      #pragma unroll
      for (int r = 0; r < 4; ++r) {
        float v0 = g4_0[r], v1 = g4_1[r];
        v0 += __shfl_xor(v0, 1);  v1 += __shfl_xor(v1, 1);
        v0 += __shfl_xor(v0, 2);  v1 += __shfl_xor(v1, 2);
        v0 += __shfl_xor(v0, 4);  v1 += __shfl_xor(v1, 4);
        v0 += __shfl_xor(v0, 8);  v1 += __shfl_xor(v1, 8);
        const int srow = lg*4 + r;
        float wr0 = __shfl(w0, srow);
        float wr1 = __shfl(w1, srow);
        float g0 = (v0 + vb2v) * wr0;
        float g1 = (v1 + vb2v) * wr1;
        float d0x = __shfl(dir0x, srow), d0y = __shfl(dir0y, srow), d0z = __shfl(dir0z, srow);
        float d1x = __shfl(dir1x, srow), d1y = __shfl(dir1y, srow), d1z = __shfl(dir1z, srow);
        if (l15 == 0) {
          vmx = fmaf(g0, d0x, fmaf(g1, d1x, vmx));
          vmy = fmaf(g0, d0y, fmaf(g1, d1y, vmy));
          vmz = fmaf(g0, d0z, fmaf(g1, d1z, vmz));
        }
      }
    }
  }

  // -------- epilogue --------
  float* Spart = scr2;             // [4][128]
  float* SL    = scr2 + 512;
  float* partA = scr2 + 640;
  float* msgL  = scr2 + 768;
  float* u1L   = scr2 + 896;
  float* xoL   = scr2 + 1024;

  #pragma unroll
  for (int kk = 0; kk < 4; ++kk)
    #pragma unroll
    for (int m = 0; m < 4; ++m) {
      float va = Sp[kk][m].x, vb = Sp[kk][m].y;
      va += __shfl_xor(va, 1);  vb += __shfl_xor(vb, 1);
      va += __shfl_xor(va, 2);  vb += __shfl_xor(vb, 2);
      va += __shfl_xor(va, 4);  vb += __shfl_xor(vb, 4);
      va += __shfl_xor(va, 8);  vb += __shfl_xor(vb, 8);
      Sp[kk][m].x = va; Sp[kk][m].y = vb;
    }
  if (l15 == 0) {
    #pragma unroll
    for (int kk = 0; kk < 4; ++kk)
      #pragma unroll
      for (int m = 0; m < 4; ++m) {
        Spart[w*128 + kk*32 + lg*8 + m*2 + 0] = Sp[kk][m].x;
        Spart[w*128 + kk*32 + lg*8 + m*2 + 1] = Sp[kk][m].y;
      }
  }
  {
    float sw = swacc;
    #pragma unroll
    for (int off = 1; off < 64; off <<= 1) sw += __shfl_xor(sw, off);
    if (l == 0) redS[w] = sw;
  }
  {
    float vx = vmx, vy = vmy, vz = vmz;
    #pragma unroll
    for (int off = 1; off < 64; off <<= 1) {
      vx += __shfl_xor(vx, off);
      vy += __shfl_xor(vy, off);
      vz += __shfl_xor(vz, off);
    }
    if (l == 0) { redVx[w] = vx; redVy[w] = vy; redVz[w] = vz; }
  }
  __syncthreads();
  if (tid < 128) SL[tid] = Spart[tid] + Spart[128+tid] + Spart[256+tid] + Spart[384+tid];
  if (tid == 0) {
    vout[ni*3 + 0] = vf[ni*3 + 0] + redVx[0]+redVx[1]+redVx[2]+redVx[3];
    vout[ni*3 + 1] = vf[ni*3 + 1] + redVy[0]+redVy[1]+redVy[2]+redVy[3];
    vout[ni*3 + 2] = vf[ni*3 + 2] + redVz[0]+redVz[1]+redVz[2]+redVz[3];
  }
  __syncthreads();
  const float sumwv = redS[0] + redS[1] + redS[2] + redS[3];

  // message_scalar = S@eW2 + sumw*eb2  (dual accumulators)
  float p = 0.f;
  { int k0 = sub*64;
    float pa = 0.f, pb = 0.f;
    #pragma unroll 4
    for (int k = k0; k < k0 + 32; ++k) {
      pa = fmaf(SL[k], eW2[k*DD + d], pa);
      pb = fmaf(SL[k+32], eW2[(k+32)*DD + d], pb);
    }
    p = pa + pb; }
  if (sub) partA[d] = p;
  __syncthreads();
  if (!sub) msgL[d] = p + partA[d] + sumwv * eb2[d];
  __syncthreads();

  // u1 = silu([x, msg] @ sW1 + sb1)
  float q = 0.f;
  if (!sub) {
    const float* xr = sf + (size_t)ni*DD;
    float qa = 0.f, qb = 0.f;
    #pragma unroll 4
    for (int tt = 0; tt < 64; ++tt) {
      qa = fmaf(xr[tt], sW1[tt*DD + d], qa);
      qb = fmaf(xr[tt+64], sW1[(tt+64)*DD + d], qb);
    }
    q = qa + qb;
  } else {
    float qa = 0.f, qb = 0.f;
    #pragma unroll 4
    for (int tt = 0; tt < 64; ++tt) {
      qa = fmaf(msgL[tt], sW1[(128 + tt)*DD + d], qa);
      qb = fmaf(msgL[tt+64], sW1[(192 + tt)*DD + d], qb);
    }
    q = qa + qb;
  }
  if (sub) partA[d] = q;
  __syncthreads();
  if (!sub) u1L[d] = siluf_(q + partA[d] + sb1[d]);
  __syncthreads();

  // upd = u1 @ sW2 + sb2; x = sf + upd
  float r2 = 0.f;
  { int t0 = sub*64;
    float ra = 0.f, rb = 0.f;
    #pragma unroll 4
    for (int tt = t0; tt < t0 + 32; ++tt) {
      ra = fmaf(u1L[tt], sW2[tt*DD + d], ra);
      rb = fmaf(u1L[tt+32], sW2[(tt+32)*DD + d], rb);
    }
    r2 = ra + rb; }
  if (sub) partA[d] = r2;
  __syncthreads();
  if (!sub) xoL[d] = sf[(size_t)ni*DD + d] + r2 + partA[d] + sb2[d];
  __syncthreads();

  // LayerNorm
  if (tid < 128) {
    float v = xoL[tid];
    float s1 = v, s2 = v*v;
    #pragma unroll
    for (int off = 1; off < 64; off <<= 1) { s1 += __shfl_xor(s1, off); s2 += __shfl_xor(s2, off); }
    if ((tid & 63) == 0) { redA[tid >> 6] = s1; redB[tid >> 6] = s2; }
  }
  __syncthreads();
  if (tid < 128) {
    float s1 = redA[0] + redA[1], s2 = redB[0] + redB[1];
    float mu = s1 * 0.0078125f;
    float var = s2 * 0.0078125f - mu*mu;
    sout[(size_t)ni*DD + tid] = (xoL[tid] - mu) * rsqrtf(var + 1e-5f) * lnw[tid] + lnb[tid];
  }
}

extern "C" void kernel_launch(void* const* d_in, const int* in_sizes, int n_in,
                              void* d_out, int out_size, void* d_ws, size_t ws_size,
                              hipStream_t stream) {
  const float* sf   = (const float*)d_in[0];
  const float* vf   = (const float*)d_in[1];
  const float* pos  = (const float*)d_in[2];
  const float* pm   = (const float*)d_in[3];
  const float* cons = (const float*)d_in[4];
  const float* eW1  = (const float*)d_in[5];
  const float* eb1  = (const float*)d_in[6];
  const float* eW2  = (const float*)d_in[7];
  const float* eb2  = (const float*)d_in[8];
  const float* sW1  = (const float*)d_in[9];
  const float* sb1  = (const float*)d_in[10];
  const float* sW2  = (const float*)d_in[11];
  const float* sb2  = (const float*)d_in[12];
  const float* vW1  = (const float*)d_in[13];
  const float* vb1  = (const float*)d_in[14];
  const float* vW2  = (const float*)d_in[15];
  const float* vb2  = (const float*)d_in[16];
  const float* lnw  = (const float*)d_in[17];
  const float* lnb  = (const float*)d_in[18];

  float* ws   = (float*)d_ws;
  float* Ag   = ws;                              // 1024*128 f32
  float* Bvg  = ws + 131072;                     // 1024*128 f32
  float* m2   = ws + 262144;                     // 128
  float* c1   = ws + 262272;                     // 128
  float* mb   = ws + 262400;                     // 1 (+pad)
  unsigned short* E2V1T = (unsigned short*)(ws + 262404); // 128*128 bf16, 16B-aligned

  float* sout  = (float*)d_out;      // [2,512,128]
  float* vout  = sout + 131072;      // [2,512,3]
  float* ewout = sout + 134144;      // [2,512,512]

  hipLaunchKernelGGL(prep_kernel, dim3(NODES + 129), dim3(128), 0, stream,
                     sf, cons, eW1, eb1, eW2, eb2, vW1, vb1,
                     Ag, Bvg, E2V1T, m2, c1, mb);
  hipLaunchKernelGGL(edge_kernel, dim3(NODES), dim3(256), 0, stream,
                     sf, vf, pos, pm, eW1, eW2, eb2, sW1, sb1, sW2, sb2,
                     vW2, vb2, lnw, lnb, Ag, Bvg, E2V1T, m2, c1, mb,
                     sout, vout, ewout);
}

// Round 15
// 90.496 us; speedup vs baseline: 2.4604x; 1.7132x over previous
//
#include <hip/hip_runtime.h>

#define DD 128
#define NN 512
#define NODES 1024

typedef short bf16x8 __attribute__((ext_vector_type(8)));
typedef float f32x4 __attribute__((ext_vector_type(4)));
typedef float f32x2 __attribute__((ext_vector_type(2)));

__device__ __forceinline__ float sigmoidf_(float x) {
  return __builtin_amdgcn_rcpf(1.f + __expf(-x));
}
__device__ __forceinline__ float siluf_(float x) { return x * sigmoidf_(x); }

__device__ __forceinline__ unsigned short f2bf_(float v) {
  unsigned int u = __float_as_uint(v);
  u += 0x7fffu + ((u >> 16) & 1u);   // RNE
  return (unsigned short)(u >> 16);
}
__device__ __forceinline__ unsigned cvtpk_(float lo, float hi) {
  unsigned r;
  asm("v_cvt_pk_bf16_f32 %0, %1, %2" : "=v"(r) : "v"(lo), "v"(hi));
  return r;
}
__device__ __forceinline__ float bflo_(unsigned u) { return __uint_as_float(u << 16); }
__device__ __forceinline__ float bfhi_(unsigned u) { return __uint_as_float(u & 0xffff0000u); }

// ---- packed f32 pairs via NATIVE vector ops (compiler emits v_pk_*_f32) ----
__device__ __forceinline__ f32x2 pk_fma(f32x2 a, f32x2 b, f32x2 c) {
  return __builtin_elementwise_fma(a, b, c);
}
__device__ __forceinline__ f32x2 mk2(float a, float b) { return (f32x2){a, b}; }
__device__ __forceinline__ f32x2 bc2(float a) { return (f32x2){a, a}; }

__device__ __forceinline__ f32x2 silu2_(f32x2 p) {
  f32x2 np = -p;
  f32x2 e;
  e.x = __expf(np.x);
  e.y = __expf(np.y);
  f32x2 den = e + bc2(1.f);
  f32x2 r;
  r.x = __builtin_amdgcn_rcpf(den.x);
  r.y = __builtin_amdgcn_rcpf(den.y);
  return p * r;
}

// ---------------- prep kernel ----------------
__global__ __launch_bounds__(128) void prep_kernel(
    const float* __restrict__ sf, const float* __restrict__ cons,
    const float* __restrict__ eW1, const float* __restrict__ eb1,
    const float* __restrict__ eW2, const float* __restrict__ eb2,
    const float* __restrict__ vW1, const float* __restrict__ vb1,
    float* __restrict__ Ag, float* __restrict__ Bvg,
    unsigned short* __restrict__ E2V1T, float* __restrict__ m2,
    float* __restrict__ c1, float* __restrict__ mb)
{
  const int bid = blockIdx.x;
  const int d = threadIdx.x;
  if (bid < NODES) {
    float c = cons[bid];
    float aacc = c * eW1[258*DD + d];
    float bacc = eb1[d] + c * eW1[257*DD + d];
    const float* sfrow = sf + bid*DD;
    #pragma unroll 4
    for (int k = 0; k < DD; ++k) {
      float s = sfrow[k];
      aacc = fmaf(s, eW1[(128+k)*DD + d], aacc);
      bacc = fmaf(s, eW1[k*DD + d], bacc);
    }
    Ag[bid*DD + d]  = aacc;
    Bvg[bid*DD + d] = bacc;
  } else if (bid < NODES + 128) {
    // E2V1T[d][k^swz] = sum_t eW2[k,t]*vW1[t,d]  (bf16, pre-swizzled)
    const int k = bid - NODES;
    float acc = 0.f;
    #pragma unroll 4
    for (int t = 0; t < DD; ++t) acc = fmaf(eW2[k*DD + t], vW1[t*DD + d], acc);
    E2V1T[d*DD + (k ^ ((d & 7) << 3))] = f2bf_(acc);
    if (d == 0) {
      float s = 0.f;
      for (int t = 0; t < DD; ++t) s += eW2[k*DD + t];
      m2[k] = s * (1.0f/128.0f);
    }
  } else {
    float acc = vb1[d];
    #pragma unroll 4
    for (int k = 0; k < DD; ++k) acc = fmaf(eb2[k], vW1[k*DD + d], acc);
    c1[d] = acc;
    if (d == 0) {
      float s = 0.f;
      for (int k = 0; k < DD; ++k) s += eb2[k];
      mb[0] = s * (1.0f/128.0f);
    }
  }
}

// ---------------- main kernel: one block per (b,i); 2 rows/lane, pk-f32 via vector ops ----------------
__global__ __launch_bounds__(256, 2) void edge_kernel(
    const float* __restrict__ sf, const float* __restrict__ vf,
    const float* __restrict__ pos, const float* __restrict__ pm,
    const float* __restrict__ eW1,
    const float* __restrict__ eW2, const float* __restrict__ eb2,
    const float* __restrict__ sW1, const float* __restrict__ sb1,
    const float* __restrict__ sW2, const float* __restrict__ sb2,
    const float* __restrict__ vW2g, const float* __restrict__ vb2g,
    const float* __restrict__ lnw, const float* __restrict__ lnb,
    const float* __restrict__ Ag, const float* __restrict__ Bvg,
    const unsigned short* __restrict__ E2V1Tg, const float* __restrict__ m2g,
    const float* __restrict__ c1g, const float* __restrict__ mbg,
    float* __restrict__ sout, float* __restrict__ vout, float* __restrict__ ewout)
{
  __shared__ __align__(16) unsigned short eTs[128*128];   // 32 KB
  __shared__ __align__(16) float BvL[DD], w256L[DD], w259L[DD], m2L[DD];
  __shared__ __align__(16) float c1L[DD], vw2L[DD];
  __shared__ __align__(16) float scr2[1152];
  __shared__ float redS[4], redVx[4], redVy[4], redVz[4], redA[2], redB[2];

  const int tid = threadIdx.x;
  const int ni  = blockIdx.x;
  const int nb  = ni & ~(NN - 1);

  const int l   = tid & 63, w = tid >> 6;
  const int l15 = l & 15,  lg = l >> 4;
  const int d   = tid & 127, sub = tid >> 7;
  const int d0base = lg*8;

  // stage E2V1 (pre-swizzled bf16) into LDS
  {
    const uint4* src = (const uint4*)E2V1Tg;
    uint4* dst = (uint4*)eTs;
    #pragma unroll
    for (int it = 0; it < 8; ++it) dst[tid + it*256] = src[tid + it*256];
  }
  if (tid < 128) {
    BvL[tid]   = Bvg[(size_t)ni*DD + tid];
    w256L[tid] = eW1[256*DD + tid];
    w259L[tid] = eW1[259*DD + tid];
    m2L[tid]   = m2g[tid];
    c1L[tid]   = c1g[tid];
    vw2L[tid]  = vW2g[tid];
  }
  const float pix = pos[ni*3+0], piy = pos[ni*3+1], piz = pos[ni*3+2];
  const float mbv = mbg[0], vb2v = vb2g[0];

  f32x2 Sp[4][4];
  #pragma unroll
  for (int kk = 0; kk < 4; ++kk)
    #pragma unroll
    for (int m = 0; m < 4; ++m) Sp[kk][m] = (f32x2){0.f, 0.f};
  float vmx = 0.f, vmy = 0.f, vmz = 0.f, swacc = 0.f;

  __syncthreads();

  for (int t = 0; t < 4; ++t) {
    const int row0 = t*128 + w*16 + l15;
    const int row1 = row0 + 64;
    float p0x = pos[(nb + row0)*3 + 0], p0y = pos[(nb + row0)*3 + 1], p0z = pos[(nb + row0)*3 + 2];
    float p1x = pos[(nb + row1)*3 + 0], p1y = pos[(nb + row1)*3 + 1], p1z = pos[(nb + row1)*3 + 2];
    float r0x = pix - p0x, r0y = piy - p0y, r0z = piz - p0z;
    float r1x = pix - p1x, r1y = piy - p1y, r1z = piz - p1z;
    float dist0 = fmaxf(sqrtf(r0x*r0x + r0y*r0y + r0z*r0z), 1e-8f);
    float dist1 = fmaxf(sqrtf(r1x*r1x + r1y*r1y + r1z*r1z), 1e-8f);
    float inv0 = __builtin_amdgcn_rcpf(dist0);
    float inv1 = __builtin_amdgcn_rcpf(dist1);
    float dir0x = r0x*inv0, dir0y = r0y*inv0, dir0z = r0z*inv0;
    float dir1x = r1x*inv1, dir1y = r1y*inv1, dir1z = r1z*inv1;
    float mj0 = pm[(size_t)ni*NN + row0];
    float mj1 = pm[(size_t)ni*NN + row1];

    const f32x2 distp0 = bc2(dist0), distp1 = bc2(dist1);
    const f32x2 mjp0 = bc2(mj0), mjp1 = bc2(mj1);

    // ---- A: h for both rows in MFMA A-frag layout, paired f32 pipeline ----
    uint4 pkA0, pkA1, pkA2, pkA3, pkB0, pkB1, pkB2, pkB3;
    f32x2 dotp0 = {0.f,0.f}, dotp1 = {0.f,0.f};
    const float* ag0 = Ag + (size_t)(nb + row0)*DD;
    const float* ag1 = Ag + (size_t)(nb + row1)*DD;

#define H_PAIR(BP, WAP, WBP, AP, DISTP, MJP) \
    silu2_(pk_fma(MJP, WBP, pk_fma(DISTP, WAP, (BP) + (AP))))

#define A_STEP2(KK, PKA, PKB) {                                                   \
    const int d0 = (KK)*32 + d0base;                                              \
    float4 b0 = *(const float4*)&BvL[d0],   b1 = *(const float4*)&BvL[d0+4];      \
    float4 wa0= *(const float4*)&w256L[d0], wa1= *(const float4*)&w256L[d0+4];    \
    float4 wb0= *(const float4*)&w259L[d0], wb1= *(const float4*)&w259L[d0+4];    \
    float4 m20= *(const float4*)&m2L[d0],   m21= *(const float4*)&m2L[d0+4];      \
    float4 aa0 = *(const float4*)(ag0 + d0), aa1 = *(const float4*)(ag0 + d0 + 4);\
    float4 ba0 = *(const float4*)(ag1 + d0), ba1 = *(const float4*)(ag1 + d0 + 4);\
    f32x2 hA0 = H_PAIR(mk2(b0.x,b0.y), mk2(wa0.x,wa0.y), mk2(wb0.x,wb0.y), mk2(aa0.x,aa0.y), distp0, mjp0); \
    f32x2 hA1 = H_PAIR(mk2(b0.z,b0.w), mk2(wa0.z,wa0.w), mk2(wb0.z,wb0.w), mk2(aa0.z,aa0.w), distp0, mjp0); \
    f32x2 hA2 = H_PAIR(mk2(b1.x,b1.y), mk2(wa1.x,wa1.y), mk2(wb1.x,wb1.y), mk2(aa1.x,aa1.y), distp0, mjp0); \
    f32x2 hA3 = H_PAIR(mk2(b1.z,b1.w), mk2(wa1.z,wa1.w), mk2(wb1.z,wb1.w), mk2(aa1.z,aa1.w), distp0, mjp0); \
    f32x2 hB0 = H_PAIR(mk2(b0.x,b0.y), mk2(wa0.x,wa0.y), mk2(wb0.x,wb0.y), mk2(ba0.x,ba0.y), distp1, mjp1); \
    f32x2 hB1 = H_PAIR(mk2(b0.z,b0.w), mk2(wa0.z,wa0.w), mk2(wb0.z,wb0.w), mk2(ba0.z,ba0.w), distp1, mjp1); \
    f32x2 hB2 = H_PAIR(mk2(b1.x,b1.y), mk2(wa1.x,wa1.y), mk2(wb1.x,wb1.y), mk2(ba1.x,ba1.y), distp1, mjp1); \
    f32x2 hB3 = H_PAIR(mk2(b1.z,b1.w), mk2(wa1.z,wa1.w), mk2(wb1.z,wb1.w), mk2(ba1.z,ba1.w), distp1, mjp1); \
    PKA.x = cvtpk_(hA0.x, hA0.y); PKA.y = cvtpk_(hA1.x, hA1.y);                   \
    PKA.z = cvtpk_(hA2.x, hA2.y); PKA.w = cvtpk_(hA3.x, hA3.y);                   \
    PKB.x = cvtpk_(hB0.x, hB0.y); PKB.y = cvtpk_(hB1.x, hB1.y);                   \
    PKB.z = cvtpk_(hB2.x, hB2.y); PKB.w = cvtpk_(hB3.x, hB3.y);                   \
    dotp0 = pk_fma(hA0, mk2(m20.x,m20.y), dotp0);                                 \
    dotp0 = pk_fma(hA1, mk2(m20.z,m20.w), dotp0);                                 \
    dotp0 = pk_fma(hA2, mk2(m21.x,m21.y), dotp0);                                 \
    dotp0 = pk_fma(hA3, mk2(m21.z,m21.w), dotp0);                                 \
    dotp1 = pk_fma(hB0, mk2(m20.x,m20.y), dotp1);                                 \
    dotp1 = pk_fma(hB1, mk2(m20.z,m20.w), dotp1);                                 \
    dotp1 = pk_fma(hB2, mk2(m21.x,m21.y), dotp1);                                 \
    dotp1 = pk_fma(hB3, mk2(m21.z,m21.w), dotp1); }

    A_STEP2(0, pkA0, pkB0)
    A_STEP2(1, pkA1, pkB1)
    A_STEP2(2, pkA2, pkB2)
    A_STEP2(3, pkA3, pkB3)
#undef A_STEP2
#undef H_PAIR

    float dot0 = dotp0.x + dotp0.y;
    float dot1 = dotp1.x + dotp1.y;
    dot0 += __shfl_xor(dot0, 16);
    dot0 += __shfl_xor(dot0, 32);
    dot1 += __shfl_xor(dot1, 16);
    dot1 += __shfl_xor(dot1, 32);
    const float w0 = mj0 * sigmoidf_(dot0 + mbv);
    const float w1 = mj1 * sigmoidf_(dot1 + mbv);
    if (lg == 0) {
      ewout[(size_t)ni*NN + row0] = w0;
      ewout[(size_t)ni*NN + row1] = w1;
      swacc += w0 + w1;
    }
    const f32x2 w0p = bc2(w0), w1p = bc2(w1);

#define S_STEP2(KK, PKA, PKB) {                                                     \
    Sp[KK][0] = pk_fma(w1p, mk2(bflo_(PKB.x), bfhi_(PKB.x)),                        \
                pk_fma(w0p, mk2(bflo_(PKA.x), bfhi_(PKA.x)), Sp[KK][0]));           \
    Sp[KK][1] = pk_fma(w1p, mk2(bflo_(PKB.y), bfhi_(PKB.y)),                        \
                pk_fma(w0p, mk2(bflo_(PKA.y), bfhi_(PKA.y)), Sp[KK][1]));           \
    Sp[KK][2] = pk_fma(w1p, mk2(bflo_(PKB.z), bfhi_(PKB.z)),                        \
                pk_fma(w0p, mk2(bflo_(PKA.z), bfhi_(PKA.z)), Sp[KK][2]));           \
    Sp[KK][3] = pk_fma(w1p, mk2(bflo_(PKB.w), bfhi_(PKB.w)),                        \
                pk_fma(w0p, mk2(bflo_(PKA.w), bfhi_(PKA.w)), Sp[KK][3])); }

    S_STEP2(0, pkA0, pkB0)
    S_STEP2(1, pkA1, pkB1)
    S_STEP2(2, pkA2, pkB2)
    S_STEP2(3, pkA3, pkB3)
#undef S_STEP2

    const bf16x8 afA0 = __builtin_bit_cast(bf16x8, pkA0);
    const bf16x8 afA1 = __builtin_bit_cast(bf16x8, pkA1);
    const bf16x8 afA2 = __builtin_bit_cast(bf16x8, pkA2);
    const bf16x8 afA3 = __builtin_bit_cast(bf16x8, pkA3);
    const bf16x8 afB0 = __builtin_bit_cast(bf16x8, pkB0);
    const bf16x8 afB1 = __builtin_bit_cast(bf16x8, pkB1);
    const bf16x8 afB2 = __builtin_bit_cast(bf16x8, pkB2);
    const bf16x8 afB3 = __builtin_bit_cast(bf16x8, pkB3);

    // ---- B: MFMA over 128 cols; gate silu on pairs ----
    f32x2 gp0a = {0.f,0.f}, gp0b = {0.f,0.f};
    f32x2 gp1a = {0.f,0.f}, gp1b = {0.f,0.f};
    #pragma unroll
    for (int ct = 0; ct < 8; ++ct) {
      const int col = ct*16 + l15;
      const int swz = (col & 7) << 3;
      const unsigned short* ecol = &eTs[col*DD];
      bf16x8 bf0 = *(const bf16x8*)&ecol[(  0 + d0base) ^ swz];
      bf16x8 bf1 = *(const bf16x8*)&ecol[( 32 + d0base) ^ swz];
      bf16x8 bf2 = *(const bf16x8*)&ecol[( 64 + d0base) ^ swz];
      bf16x8 bf3 = *(const bf16x8*)&ecol[( 96 + d0base) ^ swz];
      f32x4 c0 = {0.f,0.f,0.f,0.f};
      f32x4 c1v = {0.f,0.f,0.f,0.f};
      c0  = __builtin_amdgcn_mfma_f32_16x16x32_bf16(afA0, bf0, c0, 0, 0, 0);
      c1v = __builtin_amdgcn_mfma_f32_16x16x32_bf16(afB0, bf0, c1v, 0, 0, 0);
      c0  = __builtin_amdgcn_mfma_f32_16x16x32_bf16(afA1, bf1, c0, 0, 0, 0);
      c1v = __builtin_amdgcn_mfma_f32_16x16x32_bf16(afB1, bf1, c1v, 0, 0, 0);
      c0  = __builtin_amdgcn_mfma_f32_16x16x32_bf16(afA2, bf2, c0, 0, 0, 0);
      c1v = __builtin_amdgcn_mfma_f32_16x16x32_bf16(afB2, bf2, c1v, 0, 0, 0);
      c0  = __builtin_amdgcn_mfma_f32_16x16x32_bf16(afA3, bf3, c0, 0, 0, 0);
      c1v = __builtin_amdgcn_mfma_f32_16x16x32_bf16(afB3, bf3, c1v, 0, 0, 0);
      const f32x2 c1p = bc2(c1L[col]);
      const f32x2 vwp = bc2(vw2L[col]);
      gp0a = pk_fma(silu2_(mk2(c0[0],  c0[1])  + c1p), vwp, gp0a);
      gp0b = pk_fma(silu2_(mk2(c0[2],  c0[3])  + c1p), vwp, gp0b);
      gp1a = pk_fma(silu2_(mk2(c1v[0], c1v[1]) + c1p), vwp, gp1a);
      gp1b = pk_fma(silu2_(mk2(c1v[2], c1v[3]) + c1p), vwp, gp1b);
    }
    {
      float g4_0[4] = { gp0a.x, gp0a.y, gp0b.x, gp0b.y };
      float g4_1[4] = { gp1a.x, gp1a.y, gp1b.x, gp1b.y };
      #pragma unroll
      for (int r = 0; r < 4; ++r) {
        float v0 = g4_0[r], v1 = g4_1[r];
        v0 += __shfl_xor(v0, 1);  v1 += __shfl_xor(v1, 1);
        v0 += __shfl_xor(v0, 2);  v1 += __shfl_xor(v1, 2);
        v0 += __shfl_xor(v0, 4);  v1 += __shfl_xor(v1, 4);
        v0 += __shfl_xor(v0, 8);  v1 += __shfl_xor(v1, 8);
        const int srow = lg*4 + r;
        float wr0 = __shfl(w0, srow);
        float wr1 = __shfl(w1, srow);
        float g0 = (v0 + vb2v) * wr0;
        float g1 = (v1 + vb2v) * wr1;
        float d0x = __shfl(dir0x, srow), d0y = __shfl(dir0y, srow), d0z = __shfl(dir0z, srow);
        float d1x = __shfl(dir1x, srow), d1y = __shfl(dir1y, srow), d1z = __shfl(dir1z, srow);
        if (l15 == 0) {
          vmx = fmaf(g0, d0x, fmaf(g1, d1x, vmx));
          vmy = fmaf(g0, d0y, fmaf(g1, d1y, vmy));
          vmz = fmaf(g0, d0z, fmaf(g1, d1z, vmz));
        }
      }
    }
  }

  // -------- epilogue --------
  float* Spart = scr2;             // [4][128]
  float* SL    = scr2 + 512;
  float* partA = scr2 + 640;
  float* msgL  = scr2 + 768;
  float* u1L   = scr2 + 896;
  float* xoL   = scr2 + 1024;

  #pragma unroll
  for (int kk = 0; kk < 4; ++kk)
    #pragma unroll
    for (int m = 0; m < 4; ++m) {
      float va = Sp[kk][m].x, vb = Sp[kk][m].y;
      va += __shfl_xor(va, 1);  vb += __shfl_xor(vb, 1);
      va += __shfl_xor(va, 2);  vb += __shfl_xor(vb, 2);
      va += __shfl_xor(va, 4);  vb += __shfl_xor(vb, 4);
      va += __shfl_xor(va, 8);  vb += __shfl_xor(vb, 8);
      Sp[kk][m].x = va; Sp[kk][m].y = vb;
    }
  if (l15 == 0) {
    #pragma unroll
    for (int kk = 0; kk < 4; ++kk)
      #pragma unroll
      for (int m = 0; m < 4; ++m) {
        Spart[w*128 + kk*32 + lg*8 + m*2 + 0] = Sp[kk][m].x;
        Spart[w*128 + kk*32 + lg*8 + m*2 + 1] = Sp[kk][m].y;
      }
  }
  {
    float sw = swacc;
    #pragma unroll
    for (int off = 1; off < 64; off <<= 1) sw += __shfl_xor(sw, off);
    if (l == 0) redS[w] = sw;
  }
  {
    float vx = vmx, vy = vmy, vz = vmz;
    #pragma unroll
    for (int off = 1; off < 64; off <<= 1) {
      vx += __shfl_xor(vx, off);
      vy += __shfl_xor(vy, off);
      vz += __shfl_xor(vz, off);
    }
    if (l == 0) { redVx[w] = vx; redVy[w] = vy; redVz[w] = vz; }
  }
  __syncthreads();
  if (tid < 128) SL[tid] = Spart[tid] + Spart[128+tid] + Spart[256+tid] + Spart[384+tid];
  if (tid == 0) {
    vout[ni*3 + 0] = vf[ni*3 + 0] + redVx[0]+redVx[1]+redVx[2]+redVx[3];
    vout[ni*3 + 1] = vf[ni*3 + 1] + redVy[0]+redVy[1]+redVy[2]+redVy[3];
    vout[ni*3 + 2] = vf[ni*3 + 2] + redVz[0]+redVz[1]+redVz[2]+redVz[3];
  }
  __syncthreads();
  const float sumwv = redS[0] + redS[1] + redS[2] + redS[3];

  // message_scalar = S@eW2 + sumw*eb2  (dual accumulators)
  float p = 0.f;
  { int k0 = sub*64;
    float pa = 0.f, pb = 0.f;
    #pragma unroll 4
    for (int k = k0; k < k0 + 32; ++k) {
      pa = fmaf(SL[k], eW2[k*DD + d], pa);
      pb = fmaf(SL[k+32], eW2[(k+32)*DD + d], pb);
    }
    p = pa + pb; }
  if (sub) partA[d] = p;
  __syncthreads();
  if (!sub) msgL[d] = p + partA[d] + sumwv * eb2[d];
  __syncthreads();

  // u1 = silu([x, msg] @ sW1 + sb1)
  float q = 0.f;
  if (!sub) {
    const float* xr = sf + (size_t)ni*DD;
    float qa = 0.f, qb = 0.f;
    #pragma unroll 4
    for (int tt = 0; tt < 64; ++tt) {
      qa = fmaf(xr[tt], sW1[tt*DD + d], qa);
      qb = fmaf(xr[tt+64], sW1[(tt+64)*DD + d], qb);
    }
    q = qa + qb;
  } else {
    float qa = 0.f, qb = 0.f;
    #pragma unroll 4
    for (int tt = 0; tt < 64; ++tt) {
      qa = fmaf(msgL[tt], sW1[(128 + tt)*DD + d], qa);
      qb = fmaf(msgL[tt+64], sW1[(192 + tt)*DD + d], qb);
    }
    q = qa + qb;
  }
  if (sub) partA[d] = q;
  __syncthreads();
  if (!sub) u1L[d] = siluf_(q + partA[d] + sb1[d]);
  __syncthreads();

  // upd = u1 @ sW2 + sb2; x = sf + upd
  float r2 = 0.f;
  { int t0 = sub*64;
    float ra = 0.f, rb = 0.f;
    #pragma unroll 4
    for (int tt = t0; tt < t0 + 32; ++tt) {
      ra = fmaf(u1L[tt], sW2[tt*DD + d], ra);
      rb = fmaf(u1L[tt+32], sW2[(tt+32)*DD + d], rb);
    }
    r2 = ra + rb; }
  if (sub) partA[d] = r2;
  __syncthreads();
  if (!sub) xoL[d] = sf[(size_t)ni*DD + d] + r2 + partA[d] + sb2[d];
  __syncthreads();

  // LayerNorm
  if (tid < 128) {
    float v = xoL[tid];
    float s1 = v, s2 = v*v;
    #pragma unroll
    for (int off = 1; off < 64; off <<= 1) { s1 += __shfl_xor(s1, off); s2 += __shfl_xor(s2, off); }
    if ((tid & 63) == 0) { redA[tid >> 6] = s1; redB[tid >> 6] = s2; }
  }
  __syncthreads();
  if (tid < 128) {
    float s1 = redA[0] + redA[1], s2 = redB[0] + redB[1];
    float mu = s1 * 0.0078125f;
    float var = s2 * 0.0078125f - mu*mu;
    sout[(size_t)ni*DD + tid] = (xoL[tid] - mu) * rsqrtf(var + 1e-5f) * lnw[tid] + lnb[tid];
  }
}

extern "C" void kernel_launch(void* const* d_in, const int* in_sizes, int n_in,
                              void* d_out, int out_size, void* d_ws, size_t ws_size,
                              hipStream_t stream) {
  const float* sf   = (const float*)d_in[0];
  const float* vf   = (const float*)d_in[1];
  const float* pos  = (const float*)d_in[2];
  const float* pm   = (const float*)d_in[3];
  const float* cons = (const float*)d_in[4];
  const float* eW1  = (const float*)d_in[5];
  const float* eb1  = (const float*)d_in[6];
  const float* eW2  = (const float*)d_in[7];
  const float* eb2  = (const float*)d_in[8];
  const float* sW1  = (const float*)d_in[9];
  const float* sb1  = (const float*)d_in[10];
  const float* sW2  = (const float*)d_in[11];
  const float* sb2  = (const float*)d_in[12];
  const float* vW1  = (const float*)d_in[13];
  const float* vb1  = (const float*)d_in[14];
  const float* vW2  = (const float*)d_in[15];
  const float* vb2  = (const float*)d_in[16];
  const float* lnw  = (const float*)d_in[17];
  const float* lnb  = (const float*)d_in[18];

  float* ws   = (float*)d_ws;
  float* Ag   = ws;                              // 1024*128 f32
  float* Bvg  = ws + 131072;                     // 1024*128 f32
  float* m2   = ws + 262144;                     // 128
  float* c1   = ws + 262272;                     // 128
  float* mb   = ws + 262400;                     // 1 (+pad)
  unsigned short* E2V1T = (unsigned short*)(ws + 262404); // 128*128 bf16, 16B-aligned

  float* sout  = (float*)d_out;      // [2,512,128]
  float* vout  = sout + 131072;      // [2,512,3]
  float* ewout = sout + 134144;      // [2,512,512]

  hipLaunchKernelGGL(prep_kernel, dim3(NODES + 129), dim3(128), 0, stream,
                     sf, cons, eW1, eb1, eW2, eb2, vW1, vb1,
                     Ag, Bvg, E2V1T, m2, c1, mb);
  hipLaunchKernelGGL(edge_kernel, dim3(NODES), dim3(256), 0, stream,
                     sf, vf, pos, pm, eW1, eW2, eb2, sW1, sb1, sW2, sb2,
                     vW2, vb2, lnw, lnb, Ag, Bvg, E2V1T, m2, c1, mb,
                     sout, vout, ewout);
}